// Round 11
// baseline (511.758 us; speedup 1.0000x reference)
//
#include <hip/hip_runtime.h>
#include <stdint.h>

typedef unsigned short ushort_t;
typedef __attribute__((ext_vector_type(8))) short bf16x8;
typedef __attribute__((ext_vector_type(4))) float f32x4;

#define BB 2
#define SS 2048
#define DD 1024
#define HH 16
#define HDD 64
#define MEMM 512
#define KTOT 2560   // MEMM + SS
#define NKB 80      // KTOT/32 k-blocks
#define NTILE 160   // KTOT/16 key-tiles

// Packed V^T layout (k-PERMUTED to match the in-register score fragment):
// block (bh,kb,nt) = 512B at vt[((bh*NKB+kb)*4+nt)*512]; lane l holds 8 bf16:
//   e=0..7 -> V[k = kb*32 + (e>>2)*16 + (l>>4)*4 + (e&3)][d = nt*16 + (l&15)].
// This is exactly the order in which lane l holds scores after the swapped
// QK^T (two 16-key tiles, 4 keys each) -> P3's A-fragment comes straight from
// registers; MFMA is k-permutation-invariant when A and B share the order.

// ---------- helpers ----------
__device__ __forceinline__ float bf2f(uint32_t u) {
    return __uint_as_float(u << 16);
}
__device__ __forceinline__ ushort_t f2bf(float f) {
    uint32_t u = __float_as_uint(f);
    uint32_t r = (u + 0x7FFFu + ((u >> 16) & 1u)) >> 16;
    return (ushort_t)r;
}
__device__ __forceinline__ uint32_t mapkey(uint32_t u) {
    return (u & 0x8000u) ? (0xFFFFu ^ u) : (u | 0x8000u);
}
__device__ __forceinline__ uint32_t unmapkey(uint32_t k) {
    return (k & 0x8000u) ? (k ^ 0x8000u) : (0xFFFFu ^ k);
}

// ---------- cast hidden f32 -> bf16 ----------
__global__ __launch_bounds__(256) void cast_hidden_kernel(
    const float* __restrict__ h, ushort_t* __restrict__ hb)
{
    size_t i0 = ((size_t)blockIdx.x * 256 + threadIdx.x) * 16;  // 4M elems / 16
    ushort_t o[16];
#pragma unroll
    for (int j = 0; j < 4; ++j) {
        float4 v = *(const float4*)&h[i0 + j * 4];
        o[j * 4 + 0] = f2bf(v.x); o[j * 4 + 1] = f2bf(v.y);
        o[j * 4 + 2] = f2bf(v.z); o[j * 4 + 3] = f2bf(v.w);
    }
    *(uint4*)&hb[i0] = *(uint4*)&o[0];
    *(uint4*)&hb[i0 + 8] = *(uint4*)&o[8];
}

// ---------- transpose+cast weights: W[k][n] f32 -> Wt[n][k] bf16 ----------
__global__ __launch_bounds__(256) void transw_kernel(
    const float* __restrict__ Wq, const float* __restrict__ Wk,
    const float* __restrict__ Wv, const float* __restrict__ Wo,
    ushort_t* __restrict__ WtAll)
{
    __shared__ ushort_t T[64][66];
    const int z = blockIdx.z;
    const float* W = (z == 0) ? Wq : (z == 1) ? Wk : (z == 2) ? Wv : Wo;
    ushort_t* dst = WtAll + (size_t)z * DD * DD;
    const int k0 = blockIdx.x * 64, n0 = blockIdx.y * 64;
    const int t = threadIdx.x;
    const int kk = t >> 2, c4 = (t & 3) * 16;
#pragma unroll
    for (int j = 0; j < 4; ++j) {
        float4 v = *(const float4*)&W[(size_t)(k0 + kk) * DD + n0 + c4 + j * 4];
        T[kk][c4 + j * 4 + 0] = f2bf(v.x);
        T[kk][c4 + j * 4 + 1] = f2bf(v.y);
        T[kk][c4 + j * 4 + 2] = f2bf(v.z);
        T[kk][c4 + j * 4 + 3] = f2bf(v.w);
    }
    __syncthreads();
    const int nn = t >> 2, kc = (t & 3) * 16;
    ushort_t tmp[16];
#pragma unroll
    for (int j = 0; j < 16; ++j) tmp[j] = T[kc + j][nn];
    *(uint4*)&dst[(size_t)(n0 + nn) * DD + k0 + kc] = *(uint4*)&tmp[0];
    *(uint4*)&dst[(size_t)(n0 + nn) * DD + k0 + kc + 8] = *(uint4*)&tmp[8];
}

// ---------- 128x128-tile bf16 MFMA GEMM (m93-style LDS staging) ----------
__global__ __launch_bounds__(256) void gemm128_kernel(
    const ushort_t* __restrict__ A, const ushort_t* __restrict__ Bt, int mode,
    const float* __restrict__ bq, const float* __restrict__ bk, const float* __restrict__ bv,
    float* __restrict__ outf,
    ushort_t* __restrict__ q_bf, ushort_t* __restrict__ kbf, ushort_t* __restrict__ vbf,
    float* __restrict__ nk, float* __restrict__ nv)
{
    __shared__ __align__(16) ushort_t As[128 * 32];
    __shared__ __align__(16) ushort_t Bs[128 * 32];
    const int tid = threadIdx.x;
    const int lane = tid & 63, w = tid >> 6;
    const int wm = w >> 1, wn = w & 1;
    const int row16 = lane & 15, quad = lane >> 4;
    const int n0 = blockIdx.x * 128, m0 = blockIdx.y * 128;

    const int r0 = tid >> 2, c0 = (tid & 3) * 8;
    const int r1 = (tid + 256) >> 2, c1 = ((tid + 256) & 3) * 8;

    f32x4 acc[4][4];
#pragma unroll
    for (int i = 0; i < 4; ++i)
#pragma unroll
        for (int j = 0; j < 4; ++j) acc[i][j] = (f32x4){0.f, 0.f, 0.f, 0.f};

    for (int k0 = 0; k0 < DD; k0 += 32) {
        *(uint4*)&As[tid * 8]         = *(const uint4*)&A [(size_t)(m0 + r0) * DD + k0 + c0];
        *(uint4*)&As[(tid + 256) * 8] = *(const uint4*)&A [(size_t)(m0 + r1) * DD + k0 + c1];
        *(uint4*)&Bs[tid * 8]         = *(const uint4*)&Bt[(size_t)(n0 + r0) * DD + k0 + c0];
        *(uint4*)&Bs[(tid + 256) * 8] = *(const uint4*)&Bt[(size_t)(n0 + r1) * DD + k0 + c1];
        __syncthreads();
        bf16x8 af[4], bfr[4];
#pragma unroll
        for (int mt = 0; mt < 4; ++mt)
            af[mt] = *(const bf16x8*)&As[(wm * 64 + mt * 16 + row16) * 32 + quad * 8];
#pragma unroll
        for (int nt = 0; nt < 4; ++nt)
            bfr[nt] = *(const bf16x8*)&Bs[(wn * 64 + nt * 16 + row16) * 32 + quad * 8];
#pragma unroll
        for (int mt = 0; mt < 4; ++mt)
#pragma unroll
            for (int nt = 0; nt < 4; ++nt)
                acc[mt][nt] = __builtin_amdgcn_mfma_f32_16x16x32_bf16(
                    af[mt], bfr[nt], acc[mt][nt], 0, 0, 0);
        __syncthreads();
    }

#pragma unroll
    for (int nt = 0; nt < 4; ++nt) {
        const int nb = n0 + wn * 64 + nt * 16;       // tile-uniform
        if (mode == 0) {
#pragma unroll
            for (int mt = 0; mt < 4; ++mt) {
#pragma unroll
                for (int r = 0; r < 4; ++r) {
                    int m = m0 + wm * 64 + mt * 16 + quad * 4 + r;
                    int n = nb + row16;
                    outf[(size_t)m * DD + n] = acc[mt][nt][r] + bq[n];
                }
            }
        } else {
            const int sel = nb >> 10;
            const float* bias = (sel == 0) ? bq : (sel == 1) ? bk : bv;
#pragma unroll
            for (int mt = 0; mt < 4; ++mt) {
#pragma unroll
                for (int r = 0; r < 4; ++r) {
                    int m = m0 + wm * 64 + mt * 16 + quad * 4 + r;
                    int nn = (nb + row16) & 1023;
                    float v = acc[mt][nt][r] + bias[nn];
                    int b = m >> 11, s = m & (SS - 1);
                    int h = nn >> 6, d = nn & 63;
                    size_t bh = (size_t)b * HH + h;
                    if (sel == 0) {
                        q_bf[(bh * SS + s) * HDD + d] = f2bf(v);
                    } else {
                        ushort_t* dst = (sel == 1) ? kbf : vbf;
                        dst[(bh * KTOT + MEMM + s) * HDD + d] = f2bf(v);
                        if (s >= SS - MEMM) {
                            float* nf = (sel == 1) ? nk : nv;
                            nf[(bh * MEMM + (s - (SS - MEMM))) * HDD + d] = v;
                        }
                    }
                }
            }
        }
    }
}

// ---------- cast past_k/past_v f32 -> bf16 cache heads ----------
__global__ __launch_bounds__(256) void cast_past_kernel(
    const float* __restrict__ pk, const float* __restrict__ pv,
    ushort_t* __restrict__ kbf, ushort_t* __restrict__ vbf)
{
    int idx = blockIdx.x * 256 + threadIdx.x;  // BB*HH*MEMM*HDD = 1048576
    int bh = idx >> 15;
    int rem = idx & 32767;
    size_t dst = (size_t)bh * KTOT * HDD + rem;
    kbf[dst] = f2bf(pk[idx]);
    vbf[dst] = f2bf(pv[idx]);
}

// ---------- transpose V -> packed, k-permuted fragment layout ----------
__global__ __launch_bounds__(256) void transpose_v_kernel(
    const ushort_t* __restrict__ vbf, ushort_t* __restrict__ vt)
{
    __shared__ ushort_t T[64][72];
    const int k0 = blockIdx.x * 64;
    const int bh = blockIdx.y;
    const int t = threadIdx.x;
    const int rr = t >> 3, cc = (t & 7) * 8;
#pragma unroll
    for (int p = 0; p < 2; ++p) {
        int kk = p * 32 + rr;
        *(uint4*)&T[kk][cc] =
            *(const uint4*)(vbf + ((size_t)bh * KTOT + k0 + kk) * HDD + cc);
    }
    __syncthreads();
    const int ld = t & 63, nt = t >> 6;
    const int sr = ld & 15, q = ld >> 4;
#pragma unroll
    for (int kbl = 0; kbl < 2; ++kbl) {
        ushort_t tmp[8];
#pragma unroll
        for (int j = 0; j < 8; ++j)
            tmp[j] = T[kbl * 32 + (j >> 2) * 16 + q * 4 + (j & 3)][nt * 16 + sr];
        *(uint4*)(vt + (((size_t)bh * NKB + (k0 >> 5) + kbl) * 4 + nt) * 512 + ld * 8)
            = *(uint4*)tmp;
    }
}

// ---------- wave helpers ----------
__device__ __forceinline__ uint32_t wave_iscan(uint32_t x, int lane) {
#pragma unroll
    for (int d = 1; d < 64; d <<= 1) {
        uint32_t t = __shfl_up(x, d, 64);
        if (lane >= d) x += t;
    }
    return x;
}
__device__ __forceinline__ void select_from_counts(
    const uint32_t* c, uint32_t R, int lane, uint32_t* bin_out, uint32_t* rem_out)
{
    uint32_t s = c[0] + c[1] + c[2] + c[3];
    uint32_t incl = wave_iscan(s, lane);
    uint32_t excl = incl - s;
    uint64_t bal = __ballot(incl > R);
    int fl = __ffsll((unsigned long long)bal) - 1;
    uint32_t exf = __shfl(excl, fl, 64);
    uint32_t c0 = __shfl(c[0], fl, 64), c1 = __shfl(c[1], fl, 64);
    uint32_t c2 = __shfl(c[2], fl, 64), c3 = __shfl(c[3], fl, 64);
    uint32_t cc[4] = {c0, c1, c2, c3};
    uint32_t cum = exf, bin = fl * 4, rem = 0;
#pragma unroll
    for (int i = 0; i < 4; ++i) {
        if (cum + cc[i] > R) { bin = fl * 4 + i; rem = R - cum; break; }
        cum += cc[i];
    }
    *bin_out = bin;
    *rem_out = rem;
}

// rank-T select over a 768-ordinal u16-packed histogram (384 words).
__device__ __forceinline__ uint32_t select768(
    const uint32_t* Hr, uint32_t T, int lane)
{
    uint32_t wd[6];
    uint32_t s = 0;
#pragma unroll
    for (int i = 0; i < 6; ++i) {
        wd[i] = Hr[lane * 6 + i];
        s += (wd[i] & 0xFFFFu) + (wd[i] >> 16);
    }
    uint32_t incl = wave_iscan(s, lane);
    uint32_t excl = incl - s;
    uint64_t bal = __ballot(incl > T);
    int fl = __ffsll((unsigned long long)bal) - 1;
    uint32_t cum = __shfl(excl, fl, 64);
    uint32_t wf[6];
#pragma unroll
    for (int i = 0; i < 6; ++i) wf[i] = __shfl(wd[i], fl, 64);
    uint32_t o = (uint32_t)fl * 12u;
#pragma unroll
    for (int i = 0; i < 12; ++i) {
        uint32_t cnt = (wf[i >> 1] >> ((i & 1) * 16)) & 0xFFFFu;
        if (cum + cnt > T) { o = (uint32_t)fl * 12u + (uint32_t)i; break; }
        cum += cnt;
    }
    return o;
}

// ---------- fused score+quantile+softmax+PV, register-resident scores ----------
// Block = one 16-row q-panel of one bh. 1024 threads = 16 waves.
// P1: wave w computes tiles w*10..w*10+9 of swapped QK^T; scores stay in
//     sc[10] VGPRs (lane: q=lane&15, keys quad*4+r per tile); quantile classes
//     and the per-row 768-ordinal histogram are fed inline.
// P2: wave w selects ranks 255/256 for row w. Fallback re-streams from sc.
// P3: wave w's k-blocks (w*5..w*5+4) consume its OWN sc registers as the MFMA
//     A-fragment (vt is packed with the matching k-permutation); no S in LDS.
// launch_bounds(1024, 4): min 4 waves/EU -> 128-VGPR budget. The ~100-reg
// live set fits (no spill); R10's natural allocation chose 64 VGPR and
// SPILLED (VGPR_Count=64, WRITE_SIZE +1MB scratch). (1024,8)'s 64-VGPR
// budget is infeasible for the MFMA tuples (R8/R9 deterministic RA abort).
__global__ __launch_bounds__(1024, 4) void fused_attn_kernel(
    const ushort_t* __restrict__ qbf, const ushort_t* __restrict__ kbf,
    const ushort_t* __restrict__ vt, const int* __restrict__ amask,
    ushort_t* __restrict__ attn_bf)
{
    __shared__ __align__(16) uint32_t U[8 * 64 * 21];  // 43 KB: H (P1/P2) / red (P3)
    __shared__ uint32_t cw[16][16];                    // 1 KB
    __shared__ float thrs[16];
    __shared__ uint32_t fb[2];

    const int tid = threadIdx.x;
    const int w = tid >> 6, lane = tid & 63;
    const int row16 = lane & 15, quad = lane >> 4;
    const int bid = blockIdx.x;
    const int xcd = bid & 7, slot = bid >> 3;
    const int bh = xcd * 4 + (slot >> 7);
    const int pnl = slot & 127;
    const int b = bh >> 4, h = bh & 15;
    const int m0 = pnl * 16;
    uint32_t (*H)[385] = (uint32_t(*)[385])U;
    uint32_t* Hf = U;

    for (int i = tid; i < 16 * 385; i += 1024) U[i] = 0u;
    __syncthreads();

    // ---------------- P1: QK^T -> sc[] + inline quantile counting ----------------
    const ushort_t* qrow = qbf + ((size_t)bh * SS + m0 + row16) * HDD + quad * 8;
    bf16x8 q0 = *(const bf16x8*)qrow;
    bf16x8 q1 = *(const bf16x8*)(qrow + 32);
    const ushort_t* kbase = kbf + ((size_t)bh * KTOT + w * 160 + row16) * HDD + quad * 8;

    uint2 sc[10];
    uint32_t nBel = 0, nReg = 0;
#pragma unroll
    for (int i = 0; i < 10; ++i) {
        bf16x8 af0 = *(const bf16x8*)(kbase + (size_t)i * 16 * HDD);
        bf16x8 af1 = *(const bf16x8*)(kbase + (size_t)i * 16 * HDD + 32);
        f32x4 a4 = {0.f, 0.f, 0.f, 0.f};
        a4 = __builtin_amdgcn_mfma_f32_16x16x32_bf16(af0, q0, a4, 0, 0, 0);
        a4 = __builtin_amdgcn_mfma_f32_16x16x32_bf16(af1, q1, a4, 0, 0, 0);
        uint32_t p0, p1;
        float s0 = a4[0] * 0.125f, s1 = a4[1] * 0.125f;
        float s2 = a4[2] * 0.125f, s3 = a4[3] * 0.125f;
        asm("v_cvt_pk_bf16_f32 %0, %1, %2" : "=v"(p0) : "v"(s0), "v"(s1));
        asm("v_cvt_pk_bf16_f32 %0, %1, %2" : "=v"(p1) : "v"(s2), "v"(s3));
        sc[i].x = p0; sc[i].y = p1;
        uint32_t ww2[2] = {p0, p1};
#pragma unroll
        for (int q = 0; q < 2; ++q) {
            uint32_t t0 = (ww2[q] >> 8) & 255u, lo0 = ww2[q] & 255u;
            uint32_t t1 = ww2[q] >> 24,         lo1 = (ww2[q] >> 16) & 255u;
            nBel += (t0 >= 0xC1u);
            nBel += (t1 >= 0xC1u);
            uint32_t cls0 = 0xC0u - t0;
            uint32_t cls1 = 0xC0u - t1;
            if (cls0 <= 2u) {
                ++nReg;
                uint32_t o = cls0 * 256u + (lo0 ^ 255u);
                atomicAdd(&H[row16][o >> 1], 1u << ((o & 1u) << 4));
            }
            if (cls1 <= 2u) {
                ++nReg;
                uint32_t o = cls1 * 256u + (lo1 ^ 255u);
                atomicAdd(&H[row16][o >> 1], 1u << ((o & 1u) << 4));
            }
        }
    }
    uint32_t pk2 = nBel | (nReg << 16);
    pk2 += (uint32_t)__shfl_xor(pk2, 16, 64);
    pk2 += (uint32_t)__shfl_xor(pk2, 32, 64);
    if (lane < 16) cw[w][lane] = pk2;
    __syncthreads();

    // ---------------- P2: selection, wave w -> row w ----------------
    {
        uint32_t P = 0;
#pragma unroll
        for (int ww = 0; ww < 16; ++ww) P += cw[ww][w];
        const uint32_t c0v = P & 0xFFFFu;
        const uint32_t c3v = c0v + (P >> 16);
        if (c0v <= 255u && c3v > 256u) {
            uint32_t o0 = select768(&H[w][0], 255u - c0v, lane);
            uint32_t o1 = select768(&H[w][0], 256u - c0v, lane);
            uint32_t rawA = ((0xC0u - (o0 >> 8)) << 8) | ((o0 & 255u) ^ 255u);
            uint32_t rawB = ((0xC0u - (o1 >> 8)) << 8) | ((o1 & 255u) ^ 255u);
            if (lane == 0)
                thrs[w] = bf2f(rawA) + 0.9f * (bf2f(rawB) - bf2f(rawA));
        }
    }

    // exact fallback (rank outside 3-bin window): re-stream from sc registers.
    bool okl = false;
    if (lane < 16) {
        uint32_t Pl = 0;
#pragma unroll
        for (int ww = 0; ww < 16; ++ww) Pl += cw[ww][lane];
        uint32_t c0l = Pl & 0xFFFFu, c3l = c0l + (Pl >> 16);
        okl = (c0l <= 255u) && (c3l > 256u);
    }
    uint32_t fail = (uint32_t)__ballot(lane < 16 && !okl) & 0xFFFFu;
    while (fail) {
        const int rho = __ffs(fail) - 1; fail &= fail - 1;
        uint32_t rawAB[2] = {0u, 0u};
#pragma unroll
        for (int t2 = 0; t2 < 2; ++t2) {
            __syncthreads();
            for (int i = tid; i < 257; i += 1024) Hf[i] = 0u;
            __syncthreads();
            if (row16 == rho) {
#pragma unroll
                for (int i = 0; i < 10; ++i) {
                    uint32_t xx = sc[i].x, yy = sc[i].y;
                    atomicAdd(&Hf[mapkey(xx & 0xFFFFu) >> 8], 1u);
                    atomicAdd(&Hf[mapkey(xx >> 16) >> 8], 1u);
                    atomicAdd(&Hf[mapkey(yy & 0xFFFFu) >> 8], 1u);
                    atomicAdd(&Hf[mapkey(yy >> 16) >> 8], 1u);
                }
            }
            __syncthreads();
            if (w == 0) {
                uint32_t c4[4];
#pragma unroll
                for (int i = 0; i < 4; ++i) c4[i] = Hf[lane * 4 + i];
                uint32_t binM, rem;
                select_from_counts(c4, 255u + (uint32_t)t2, lane, &binM, &rem);
                if (lane == 0) { fb[0] = binM; fb[1] = rem; }
            }
            __syncthreads();
            const uint32_t binM = fb[0], rem = fb[1];
            for (int i = tid; i < 257; i += 1024) Hf[i] = 0u;
            __syncthreads();
            if (row16 == rho) {
#pragma unroll
                for (int i = 0; i < 10; ++i) {
                    uint32_t kk4[4] = {sc[i].x & 0xFFFFu, sc[i].x >> 16,
                                       sc[i].y & 0xFFFFu, sc[i].y >> 16};
#pragma unroll
                    for (int q = 0; q < 4; ++q) {
                        uint32_t mk = mapkey(kk4[q]);
                        if ((mk >> 8) == binM) atomicAdd(&Hf[mk & 255u], 1u);
                    }
                }
            }
            __syncthreads();
            if (w == 0) {
                uint32_t c4[4];
#pragma unroll
                for (int i = 0; i < 4; ++i) c4[i] = Hf[lane * 4 + i];
                uint32_t low, r2;
                select_from_counts(c4, rem, lane, &low, &r2);
                rawAB[t2] = unmapkey((binM << 8) | low);
            }
        }
        __syncthreads();
        if (tid == 0) {
            float fA = bf2f(rawAB[0]), fB = bf2f(rawAB[1]);
            thrs[rho] = fA + 0.9f * (fB - fA);
        }
        __syncthreads();
    }
    __syncthreads();

    // ---------------- P3: softmax + PV from registers ----------------
    const float thr = thrs[row16];
    const int* amq2 = amask + b * SS + quad * 4;
    const ushort_t* bbase = vt + (size_t)bh * NKB * 2048 + lane * 8;

    const uint32_t ow = (row16 == 0) ? 0x3F803F80u : 0u;
    uint4 ov; ov.x = ow; ov.y = ow; ov.z = ow; ov.w = ow;
    bf16x8 onesf; *(uint4*)&onesf = ov;

    f32x4 acc[4];
#pragma unroll
    for (int i = 0; i < 4; ++i) acc[i] = (f32x4){0.f, 0.f, 0.f, 0.f};
    f32x4 acc5 = (f32x4){0.f, 0.f, 0.f, 0.f};

#pragma unroll
    for (int j = 0; j < 5; ++j) {
        const int kb = w * 5 + j;
        uint4 bfrag[4];
#pragma unroll
        for (int nt = 0; nt < 4; ++nt)
            bfrag[nt] = *(const uint4*)(bbase + (size_t)kb * 2048 + nt * 512);
        const bool masked = (kb >= 16);
        int4 mv0 = {1, 1, 1, 1}, mv1 = {1, 1, 1, 1};
        if (masked) {
            mv0 = *(const int4*)(amq2 + kb * 32 - MEMM);
            mv1 = *(const int4*)(amq2 + kb * 32 - MEMM + 16);
        }
        const uint2 sA = sc[2 * j], sB = sc[2 * j + 1];
        uint32_t u[8] = {sA.x & 0xFFFFu, sA.x >> 16, sA.y & 0xFFFFu, sA.y >> 16,
                         sB.x & 0xFFFFu, sB.x >> 16, sB.y & 0xFFFFu, sB.y >> 16};
        int mm[8] = {mv0.x, mv0.y, mv0.z, mv0.w, mv1.x, mv1.y, mv1.z, mv1.w};
        float wv[8];
#pragma unroll
        for (int e = 0; e < 8; ++e) {
            float s = bf2f(u[e]);
            bool keep = (s >= thr);
            if (masked) keep = keep && (mm[e] != 0);
            wv[e] = keep ? __expf(s) : 0.f;
        }
        uint4 aq;
        asm("v_cvt_pk_bf16_f32 %0, %1, %2" : "=v"(aq.x) : "v"(wv[0]), "v"(wv[1]));
        asm("v_cvt_pk_bf16_f32 %0, %1, %2" : "=v"(aq.y) : "v"(wv[2]), "v"(wv[3]));
        asm("v_cvt_pk_bf16_f32 %0, %1, %2" : "=v"(aq.z) : "v"(wv[4]), "v"(wv[5]));
        asm("v_cvt_pk_bf16_f32 %0, %1, %2" : "=v"(aq.w) : "v"(wv[6]), "v"(wv[7]));
        bf16x8 af;
        *(uint4*)&af = aq;
#pragma unroll
        for (int nt = 0; nt < 4; ++nt) {
            bf16x8 bf;
            *(uint4*)&bf = bfrag[nt];
            acc[nt] = __builtin_amdgcn_mfma_f32_16x16x32_bf16(af, bf, acc[nt], 0, 0, 0);
        }
        acc5 = __builtin_amdgcn_mfma_f32_16x16x32_bf16(af, onesf, acc5, 0, 0, 0);
    }

    // ---- combine 16 waves -> wave 0 (red aliases U: hist dead) ----
    __syncthreads();
    float* redf = (float*)U;   // [8][64][21] = 43 KB
#define RED(i) (redf + ((size_t)(i) * 64 + lane) * 21)
    if (w >= 8) {
        float* d = RED(w - 8);
#pragma unroll
        for (int nt = 0; nt < 4; ++nt)
#pragma unroll
            for (int r = 0; r < 4; ++r) d[nt * 4 + r] = acc[nt][r];
#pragma unroll
        for (int r = 0; r < 4; ++r) d[16 + r] = acc5[r];
    }
    __syncthreads();
    if (w < 8) {
        const float* s = RED(w);
#pragma unroll
        for (int nt = 0; nt < 4; ++nt)
#pragma unroll
            for (int r = 0; r < 4; ++r) acc[nt][r] += s[nt * 4 + r];
#pragma unroll
        for (int r = 0; r < 4; ++r) acc5[r] += s[16 + r];
    }
    __syncthreads();
    if (w >= 4 && w < 8) {
        float* d = RED(w - 4);
#pragma unroll
        for (int nt = 0; nt < 4; ++nt)
#pragma unroll
            for (int r = 0; r < 4; ++r) d[nt * 4 + r] = acc[nt][r];
#pragma unroll
        for (int r = 0; r < 4; ++r) d[16 + r] = acc5[r];
    }
    __syncthreads();
    if (w < 4) {
        const float* s = RED(w);
#pragma unroll
        for (int nt = 0; nt < 4; ++nt)
#pragma unroll
            for (int r = 0; r < 4; ++r) acc[nt][r] += s[nt * 4 + r];
#pragma unroll
        for (int r = 0; r < 4; ++r) acc5[r] += s[16 + r];
    }
    __syncthreads();
    if (w >= 2 && w < 4) {
        float* d = RED(w - 2);
#pragma unroll
        for (int nt = 0; nt < 4; ++nt)
#pragma unroll
            for (int r = 0; r < 4; ++r) d[nt * 4 + r] = acc[nt][r];
#pragma unroll
        for (int r = 0; r < 4; ++r) d[16 + r] = acc5[r];
    }
    __syncthreads();
    if (w < 2) {
        const float* s = RED(w);
#pragma unroll
        for (int nt = 0; nt < 4; ++nt)
#pragma unroll
            for (int r = 0; r < 4; ++r) acc[nt][r] += s[nt * 4 + r];
#pragma unroll
        for (int r = 0; r < 4; ++r) acc5[r] += s[16 + r];
    }
    __syncthreads();
    if (w == 1) {
        float* d = RED(0);
#pragma unroll
        for (int nt = 0; nt < 4; ++nt)
#pragma unroll
            for (int r = 0; r < 4; ++r) d[nt * 4 + r] = acc[nt][r];
#pragma unroll
        for (int r = 0; r < 4; ++r) d[16 + r] = acc5[r];
    }
    __syncthreads();
    if (w == 0) {
        const float* s = RED(0);
#pragma unroll
        for (int nt = 0; nt < 4; ++nt)
#pragma unroll
            for (int r = 0; r < 4; ++r) acc[nt][r] += s[nt * 4 + r];
#pragma unroll
        for (int r = 0; r < 4; ++r) acc5[r] += s[16 + r];

        float rinv[4];
#pragma unroll
        for (int r = 0; r < 4; ++r) {
            float rs = __shfl(acc5[r], quad * 16, 64);
            rinv[r] = 1.0f / rs;
        }
#pragma unroll
        for (int nt = 0; nt < 4; ++nt) {
#pragma unroll
            for (int r = 0; r < 4; ++r) {
                int row = quad * 4 + r;
                float val = acc[nt][r] * rinv[r];
                attn_bf[((size_t)b * SS + m0 + row) * DD + h * HDD + nt * 16 + row16] = f2bf(val);
            }
        }
    }
#undef RED
}

extern "C" void kernel_launch(void* const* d_in, const int* in_sizes, int n_in,
                              void* d_out, int out_size, void* d_ws, size_t ws_size,
                              hipStream_t stream)
{
    const float* hidden = (const float*)d_in[0];
    const int*   amask  = (const int*)d_in[1];
    const float* past_k = (const float*)d_in[2];
    const float* past_v = (const float*)d_in[3];
    const float* Wq = (const float*)d_in[4];
    const float* bq = (const float*)d_in[5];
    const float* Wk = (const float*)d_in[6];
    const float* bk = (const float*)d_in[7];
    const float* Wv = (const float*)d_in[8];
    const float* bv = (const float*)d_in[9];
    const float* Wo = (const float*)d_in[10];
    const float* bo = (const float*)d_in[11];

    float* out    = (float*)d_out;
    float* nk_out = out + (size_t)BB * SS * DD;
    float* nv_out = nk_out + (size_t)BB * HH * MEMM * HDD;

    char* base = (char*)d_ws;
    size_t off = 0;
    auto alloc = [&](size_t bytes) {
        char* p = base + off;
        off += (bytes + 255) & ~(size_t)255;
        return p;
    };
    ushort_t* hb    = (ushort_t*)alloc((size_t)BB * SS * DD * 2);            // 8 MB
    ushort_t* WtAll = (ushort_t*)alloc((size_t)4 * DD * DD * 2);             // 8 MB
    ushort_t* q_bf  = (ushort_t*)alloc((size_t)BB * HH * SS * HDD * 2);      // 8 MB
    ushort_t* kbf   = (ushort_t*)alloc((size_t)BB * HH * KTOT * HDD * 2);    // 10 MB
    ushort_t* vbf   = (ushort_t*)alloc((size_t)BB * HH * KTOT * HDD * 2);    // 10 MB
    ushort_t* vt    = (ushort_t*)alloc((size_t)BB * HH * NKB * 4 * 512 * 2); // 10.5 MB packed
    ushort_t* abf   = (ushort_t*)alloc((size_t)BB * SS * DD * 2);            // 8 MB

    dim3 blk(256);

    cast_hidden_kernel<<<dim3(1024), blk, 0, stream>>>(hidden, hb);
    transw_kernel<<<dim3(16, 16, 4), blk, 0, stream>>>(Wq, Wk, Wv, Wo, WtAll);
    // fused QKV: one GEMM, N=3072 (Wq|Wk|Wv transposes adjacent in WtAll)
    gemm128_kernel<<<dim3(24, 32), blk, 0, stream>>>(
        hb, WtAll, 1, bq, bk, bv, nullptr, q_bf, kbf, vbf, nk_out, nv_out);
    cast_past_kernel<<<dim3(4096), blk, 0, stream>>>(past_k, past_v, kbf, vbf);
    transpose_v_kernel<<<dim3(KTOT / 64, BB * HH), blk, 0, stream>>>(vbf, vt);

    // fused attention: one 16-wave block per 16-row panel, scores in registers
    fused_attn_kernel<<<dim3(BB * HH * (SS / 16)), dim3(1024), 0, stream>>>(
        q_bf, kbf, vt, amask, abf);

    // O-projection
    gemm128_kernel<<<dim3(8, 32), blk, 0, stream>>>(
        abf, WtAll + (size_t)3 * DD * DD, 0, bo, nullptr, nullptr, out,
        nullptr, nullptr, nullptr, nullptr, nullptr);
}

// Round 12
// 507.216 us; speedup vs baseline: 1.0090x; 1.0090x over previous
//
#include <hip/hip_runtime.h>
#include <stdint.h>

typedef unsigned short ushort_t;
typedef __attribute__((ext_vector_type(8))) short bf16x8;
typedef __attribute__((ext_vector_type(4))) float f32x4;

#define BB 2
#define SS 2048
#define DD 1024
#define HH 16
#define HDD 64
#define MEMM 512
#define KTOT 2560   // MEMM + SS
#define NKB 80      // KTOT/32 k-blocks
#define NTILE 160   // KTOT/16 key-tiles

// Packed V^T layout (k-PERMUTED to match the in-register score fragment):
// block (bh,kb,nt) = 512B at vt[((bh*NKB+kb)*4+nt)*512]; lane l holds 8 bf16:
//   e=0..7 -> V[k = kb*32 + (e>>2)*16 + (l>>4)*4 + (e&3)][d = nt*16 + (l&15)].
// This is exactly the order in which lane l holds scores after the swapped
// QK^T (two 16-key tiles, 4 keys each) -> P3's A-fragment comes straight from
// registers; MFMA is k-permutation-invariant when A and B share the order.

// ---------- helpers ----------
__device__ __forceinline__ float bf2f(uint32_t u) {
    return __uint_as_float(u << 16);
}
__device__ __forceinline__ ushort_t f2bf(float f) {
    uint32_t u = __float_as_uint(f);
    uint32_t r = (u + 0x7FFFu + ((u >> 16) & 1u)) >> 16;
    return (ushort_t)r;
}
__device__ __forceinline__ uint32_t mapkey(uint32_t u) {
    return (u & 0x8000u) ? (0xFFFFu ^ u) : (u | 0x8000u);
}
__device__ __forceinline__ uint32_t unmapkey(uint32_t k) {
    return (k & 0x8000u) ? (k ^ 0x8000u) : (0xFFFFu ^ k);
}

// ---------- cast hidden f32 -> bf16 ----------
__global__ __launch_bounds__(256) void cast_hidden_kernel(
    const float* __restrict__ h, ushort_t* __restrict__ hb)
{
    size_t i0 = ((size_t)blockIdx.x * 256 + threadIdx.x) * 16;  // 4M elems / 16
    ushort_t o[16];
#pragma unroll
    for (int j = 0; j < 4; ++j) {
        float4 v = *(const float4*)&h[i0 + j * 4];
        o[j * 4 + 0] = f2bf(v.x); o[j * 4 + 1] = f2bf(v.y);
        o[j * 4 + 2] = f2bf(v.z); o[j * 4 + 3] = f2bf(v.w);
    }
    *(uint4*)&hb[i0] = *(uint4*)&o[0];
    *(uint4*)&hb[i0 + 8] = *(uint4*)&o[8];
}

// ---------- transpose+cast weights: W[k][n] f32 -> Wt[n][k] bf16 ----------
__global__ __launch_bounds__(256) void transw_kernel(
    const float* __restrict__ Wq, const float* __restrict__ Wk,
    const float* __restrict__ Wv, const float* __restrict__ Wo,
    ushort_t* __restrict__ WtAll)
{
    __shared__ ushort_t T[64][66];
    const int z = blockIdx.z;
    const float* W = (z == 0) ? Wq : (z == 1) ? Wk : (z == 2) ? Wv : Wo;
    ushort_t* dst = WtAll + (size_t)z * DD * DD;
    const int k0 = blockIdx.x * 64, n0 = blockIdx.y * 64;
    const int t = threadIdx.x;
    const int kk = t >> 2, c4 = (t & 3) * 16;
#pragma unroll
    for (int j = 0; j < 4; ++j) {
        float4 v = *(const float4*)&W[(size_t)(k0 + kk) * DD + n0 + c4 + j * 4];
        T[kk][c4 + j * 4 + 0] = f2bf(v.x);
        T[kk][c4 + j * 4 + 1] = f2bf(v.y);
        T[kk][c4 + j * 4 + 2] = f2bf(v.z);
        T[kk][c4 + j * 4 + 3] = f2bf(v.w);
    }
    __syncthreads();
    const int nn = t >> 2, kc = (t & 3) * 16;
    ushort_t tmp[16];
#pragma unroll
    for (int j = 0; j < 16; ++j) tmp[j] = T[kc + j][nn];
    *(uint4*)&dst[(size_t)(n0 + nn) * DD + k0 + kc] = *(uint4*)&tmp[0];
    *(uint4*)&dst[(size_t)(n0 + nn) * DD + k0 + kc + 8] = *(uint4*)&tmp[8];
}

// ---------- 128x128-tile bf16 MFMA GEMM (m93-style LDS staging) ----------
__global__ __launch_bounds__(256) void gemm128_kernel(
    const ushort_t* __restrict__ A, const ushort_t* __restrict__ Bt, int mode,
    const float* __restrict__ bq, const float* __restrict__ bk, const float* __restrict__ bv,
    float* __restrict__ outf,
    ushort_t* __restrict__ q_bf, ushort_t* __restrict__ kbf, ushort_t* __restrict__ vbf,
    float* __restrict__ nk, float* __restrict__ nv)
{
    __shared__ __align__(16) ushort_t As[128 * 32];
    __shared__ __align__(16) ushort_t Bs[128 * 32];
    const int tid = threadIdx.x;
    const int lane = tid & 63, w = tid >> 6;
    const int wm = w >> 1, wn = w & 1;
    const int row16 = lane & 15, quad = lane >> 4;
    const int n0 = blockIdx.x * 128, m0 = blockIdx.y * 128;

    const int r0 = tid >> 2, c0 = (tid & 3) * 8;
    const int r1 = (tid + 256) >> 2, c1 = ((tid + 256) & 3) * 8;

    f32x4 acc[4][4];
#pragma unroll
    for (int i = 0; i < 4; ++i)
#pragma unroll
        for (int j = 0; j < 4; ++j) acc[i][j] = (f32x4){0.f, 0.f, 0.f, 0.f};

    for (int k0 = 0; k0 < DD; k0 += 32) {
        *(uint4*)&As[tid * 8]         = *(const uint4*)&A [(size_t)(m0 + r0) * DD + k0 + c0];
        *(uint4*)&As[(tid + 256) * 8] = *(const uint4*)&A [(size_t)(m0 + r1) * DD + k0 + c1];
        *(uint4*)&Bs[tid * 8]         = *(const uint4*)&Bt[(size_t)(n0 + r0) * DD + k0 + c0];
        *(uint4*)&Bs[(tid + 256) * 8] = *(const uint4*)&Bt[(size_t)(n0 + r1) * DD + k0 + c1];
        __syncthreads();
        bf16x8 af[4], bfr[4];
#pragma unroll
        for (int mt = 0; mt < 4; ++mt)
            af[mt] = *(const bf16x8*)&As[(wm * 64 + mt * 16 + row16) * 32 + quad * 8];
#pragma unroll
        for (int nt = 0; nt < 4; ++nt)
            bfr[nt] = *(const bf16x8*)&Bs[(wn * 64 + nt * 16 + row16) * 32 + quad * 8];
#pragma unroll
        for (int mt = 0; mt < 4; ++mt)
#pragma unroll
            for (int nt = 0; nt < 4; ++nt)
                acc[mt][nt] = __builtin_amdgcn_mfma_f32_16x16x32_bf16(
                    af[mt], bfr[nt], acc[mt][nt], 0, 0, 0);
        __syncthreads();
    }

#pragma unroll
    for (int nt = 0; nt < 4; ++nt) {
        const int nb = n0 + wn * 64 + nt * 16;       // tile-uniform
        if (mode == 0) {
#pragma unroll
            for (int mt = 0; mt < 4; ++mt) {
#pragma unroll
                for (int r = 0; r < 4; ++r) {
                    int m = m0 + wm * 64 + mt * 16 + quad * 4 + r;
                    int n = nb + row16;
                    outf[(size_t)m * DD + n] = acc[mt][nt][r] + bq[n];
                }
            }
        } else {
            const int sel = nb >> 10;
            const float* bias = (sel == 0) ? bq : (sel == 1) ? bk : bv;
#pragma unroll
            for (int mt = 0; mt < 4; ++mt) {
#pragma unroll
                for (int r = 0; r < 4; ++r) {
                    int m = m0 + wm * 64 + mt * 16 + quad * 4 + r;
                    int nn = (nb + row16) & 1023;
                    float v = acc[mt][nt][r] + bias[nn];
                    int b = m >> 11, s = m & (SS - 1);
                    int h = nn >> 6, d = nn & 63;
                    size_t bh = (size_t)b * HH + h;
                    if (sel == 0) {
                        q_bf[(bh * SS + s) * HDD + d] = f2bf(v);
                    } else {
                        ushort_t* dst = (sel == 1) ? kbf : vbf;
                        dst[(bh * KTOT + MEMM + s) * HDD + d] = f2bf(v);
                        if (s >= SS - MEMM) {
                            float* nf = (sel == 1) ? nk : nv;
                            nf[(bh * MEMM + (s - (SS - MEMM))) * HDD + d] = v;
                        }
                    }
                }
            }
        }
    }
}

// ---------- cast past_k/past_v f32 -> bf16 cache heads ----------
__global__ __launch_bounds__(256) void cast_past_kernel(
    const float* __restrict__ pk, const float* __restrict__ pv,
    ushort_t* __restrict__ kbf, ushort_t* __restrict__ vbf)
{
    int idx = blockIdx.x * 256 + threadIdx.x;  // BB*HH*MEMM*HDD = 1048576
    int bh = idx >> 15;
    int rem = idx & 32767;
    size_t dst = (size_t)bh * KTOT * HDD + rem;
    kbf[dst] = f2bf(pk[idx]);
    vbf[dst] = f2bf(pv[idx]);
}

// ---------- transpose V -> packed, k-permuted fragment layout ----------
__global__ __launch_bounds__(256) void transpose_v_kernel(
    const ushort_t* __restrict__ vbf, ushort_t* __restrict__ vt)
{
    __shared__ ushort_t T[64][72];
    const int k0 = blockIdx.x * 64;
    const int bh = blockIdx.y;
    const int t = threadIdx.x;
    const int rr = t >> 3, cc = (t & 7) * 8;
#pragma unroll
    for (int p = 0; p < 2; ++p) {
        int kk = p * 32 + rr;
        *(uint4*)&T[kk][cc] =
            *(const uint4*)(vbf + ((size_t)bh * KTOT + k0 + kk) * HDD + cc);
    }
    __syncthreads();
    const int ld = t & 63, nt = t >> 6;
    const int sr = ld & 15, q = ld >> 4;
#pragma unroll
    for (int kbl = 0; kbl < 2; ++kbl) {
        ushort_t tmp[8];
#pragma unroll
        for (int j = 0; j < 8; ++j)
            tmp[j] = T[kbl * 32 + (j >> 2) * 16 + q * 4 + (j & 3)][nt * 16 + sr];
        *(uint4*)(vt + (((size_t)bh * NKB + (k0 >> 5) + kbl) * 4 + nt) * 512 + ld * 8)
            = *(uint4*)tmp;
    }
}

// ---------- wave helpers ----------
__device__ __forceinline__ uint32_t wave_iscan(uint32_t x, int lane) {
#pragma unroll
    for (int d = 1; d < 64; d <<= 1) {
        uint32_t t = __shfl_up(x, d, 64);
        if (lane >= d) x += t;
    }
    return x;
}
__device__ __forceinline__ void select_from_counts(
    const uint32_t* c, uint32_t R, int lane, uint32_t* bin_out, uint32_t* rem_out)
{
    uint32_t s = c[0] + c[1] + c[2] + c[3];
    uint32_t incl = wave_iscan(s, lane);
    uint32_t excl = incl - s;
    uint64_t bal = __ballot(incl > R);
    int fl = __ffsll((unsigned long long)bal) - 1;
    uint32_t exf = __shfl(excl, fl, 64);
    uint32_t c0 = __shfl(c[0], fl, 64), c1 = __shfl(c[1], fl, 64);
    uint32_t c2 = __shfl(c[2], fl, 64), c3 = __shfl(c[3], fl, 64);
    uint32_t cc[4] = {c0, c1, c2, c3};
    uint32_t cum = exf, bin = fl * 4, rem = 0;
#pragma unroll
    for (int i = 0; i < 4; ++i) {
        if (cum + cc[i] > R) { bin = fl * 4 + i; rem = R - cum; break; }
        cum += cc[i];
    }
    *bin_out = bin;
    *rem_out = rem;
}

// rank-T select over a 768-ordinal u16-packed histogram (384 words).
__device__ __forceinline__ uint32_t select768(
    const uint32_t* Hr, uint32_t T, int lane)
{
    uint32_t wd[6];
    uint32_t s = 0;
#pragma unroll
    for (int i = 0; i < 6; ++i) {
        wd[i] = Hr[lane * 6 + i];
        s += (wd[i] & 0xFFFFu) + (wd[i] >> 16);
    }
    uint32_t incl = wave_iscan(s, lane);
    uint32_t excl = incl - s;
    uint64_t bal = __ballot(incl > T);
    int fl = __ffsll((unsigned long long)bal) - 1;
    uint32_t cum = __shfl(excl, fl, 64);
    uint32_t wf[6];
#pragma unroll
    for (int i = 0; i < 6; ++i) wf[i] = __shfl(wd[i], fl, 64);
    uint32_t o = (uint32_t)fl * 12u;
#pragma unroll
    for (int i = 0; i < 12; ++i) {
        uint32_t cnt = (wf[i >> 1] >> ((i & 1) * 16)) & 0xFFFFu;
        if (cum + cnt > T) { o = (uint32_t)fl * 12u + (uint32_t)i; break; }
        cum += cnt;
    }
    return o;
}

// ---------- fused score+quantile+softmax+PV, register-resident scores ----------
// Block = one 16-row q-panel of one bh. 1024 threads = 16 waves.
// P1: wave w computes tiles w*10..w*10+9 of swapped QK^T; scores stay in
//     sc[10] VGPRs; quantile classes + per-row 768-ordinal hist fed inline.
// P2: wave w selects ranks 255/256 for row w. Fallback re-streams from sc.
// P3: wave w's k-blocks (w*5..w*5+4) consume its OWN sc registers as the MFMA
//     A-fragment (vt is packed with the matching k-permutation); no S in LDS.
// amdgpu_waves_per_eu(4,4): pins EXACTLY 4 waves/EU -> firm 128-VGPR budget.
// R10/R11 showed launch_bounds(1024[,4]) lets the allocator target 8 waves/EU
// (64 VGPR) and SPILL the ~100-reg live set: VALUBusy 45% (3-5x algorithmic),
// WRITE_SIZE +1MB scratch, occupancy stuck ~45%. Min-AND-max removes the
// incentive to squeeze. 128-budget is feasible ((1024,8)'s 64 was not: R8/R9).
__global__ __launch_bounds__(1024)
__attribute__((amdgpu_waves_per_eu(4, 4)))
void fused_attn_kernel(
    const ushort_t* __restrict__ qbf, const ushort_t* __restrict__ kbf,
    const ushort_t* __restrict__ vt, const int* __restrict__ amask,
    ushort_t* __restrict__ attn_bf)
{
    __shared__ __align__(16) uint32_t U[8 * 64 * 21];  // 43 KB: H (P1/P2) / red (P3)
    __shared__ uint32_t cw[16][16];                    // 1 KB
    __shared__ float thrs[16];
    __shared__ uint32_t fb[2];

    const int tid = threadIdx.x;
    const int w = tid >> 6, lane = tid & 63;
    const int row16 = lane & 15, quad = lane >> 4;
    const int bid = blockIdx.x;
    const int xcd = bid & 7, slot = bid >> 3;
    const int bh = xcd * 4 + (slot >> 7);
    const int pnl = slot & 127;
    const int b = bh >> 4, h = bh & 15;
    const int m0 = pnl * 16;
    uint32_t (*H)[385] = (uint32_t(*)[385])U;
    uint32_t* Hf = U;

    for (int i = tid; i < 16 * 385; i += 1024) U[i] = 0u;
    __syncthreads();

    // ---------------- P1: QK^T -> sc[] + inline quantile counting ----------------
    const ushort_t* qrow = qbf + ((size_t)bh * SS + m0 + row16) * HDD + quad * 8;
    bf16x8 q0 = *(const bf16x8*)qrow;
    bf16x8 q1 = *(const bf16x8*)(qrow + 32);
    const ushort_t* kbase = kbf + ((size_t)bh * KTOT + w * 160 + row16) * HDD + quad * 8;

    uint2 sc[10];
    uint32_t nBel = 0, nReg = 0;
#pragma unroll
    for (int i = 0; i < 10; ++i) {
        bf16x8 af0 = *(const bf16x8*)(kbase + (size_t)i * 16 * HDD);
        bf16x8 af1 = *(const bf16x8*)(kbase + (size_t)i * 16 * HDD + 32);
        f32x4 a4 = {0.f, 0.f, 0.f, 0.f};
        a4 = __builtin_amdgcn_mfma_f32_16x16x32_bf16(af0, q0, a4, 0, 0, 0);
        a4 = __builtin_amdgcn_mfma_f32_16x16x32_bf16(af1, q1, a4, 0, 0, 0);
        uint32_t p0, p1;
        float s0 = a4[0] * 0.125f, s1 = a4[1] * 0.125f;
        float s2 = a4[2] * 0.125f, s3 = a4[3] * 0.125f;
        asm("v_cvt_pk_bf16_f32 %0, %1, %2" : "=v"(p0) : "v"(s0), "v"(s1));
        asm("v_cvt_pk_bf16_f32 %0, %1, %2" : "=v"(p1) : "v"(s2), "v"(s3));
        sc[i].x = p0; sc[i].y = p1;
        uint32_t ww2[2] = {p0, p1};
#pragma unroll
        for (int q = 0; q < 2; ++q) {
            uint32_t t0 = (ww2[q] >> 8) & 255u, lo0 = ww2[q] & 255u;
            uint32_t t1 = ww2[q] >> 24,         lo1 = (ww2[q] >> 16) & 255u;
            nBel += (t0 >= 0xC1u);
            nBel += (t1 >= 0xC1u);
            uint32_t cls0 = 0xC0u - t0;
            uint32_t cls1 = 0xC0u - t1;
            if (cls0 <= 2u) {
                ++nReg;
                uint32_t o = cls0 * 256u + (lo0 ^ 255u);
                atomicAdd(&H[row16][o >> 1], 1u << ((o & 1u) << 4));
            }
            if (cls1 <= 2u) {
                ++nReg;
                uint32_t o = cls1 * 256u + (lo1 ^ 255u);
                atomicAdd(&H[row16][o >> 1], 1u << ((o & 1u) << 4));
            }
        }
    }
    uint32_t pk2 = nBel | (nReg << 16);
    pk2 += (uint32_t)__shfl_xor(pk2, 16, 64);
    pk2 += (uint32_t)__shfl_xor(pk2, 32, 64);
    if (lane < 16) cw[w][lane] = pk2;
    __syncthreads();

    // ---------------- P2: selection, wave w -> row w ----------------
    {
        uint32_t P = 0;
#pragma unroll
        for (int ww = 0; ww < 16; ++ww) P += cw[ww][w];
        const uint32_t c0v = P & 0xFFFFu;
        const uint32_t c3v = c0v + (P >> 16);
        if (c0v <= 255u && c3v > 256u) {
            uint32_t o0 = select768(&H[w][0], 255u - c0v, lane);
            uint32_t o1 = select768(&H[w][0], 256u - c0v, lane);
            uint32_t rawA = ((0xC0u - (o0 >> 8)) << 8) | ((o0 & 255u) ^ 255u);
            uint32_t rawB = ((0xC0u - (o1 >> 8)) << 8) | ((o1 & 255u) ^ 255u);
            if (lane == 0)
                thrs[w] = bf2f(rawA) + 0.9f * (bf2f(rawB) - bf2f(rawA));
        }
    }

    // exact fallback (rank outside 3-bin window): re-stream from sc registers.
    bool okl = false;
    if (lane < 16) {
        uint32_t Pl = 0;
#pragma unroll
        for (int ww = 0; ww < 16; ++ww) Pl += cw[ww][lane];
        uint32_t c0l = Pl & 0xFFFFu, c3l = c0l + (Pl >> 16);
        okl = (c0l <= 255u) && (c3l > 256u);
    }
    uint32_t fail = (uint32_t)__ballot(lane < 16 && !okl) & 0xFFFFu;
    while (fail) {
        const int rho = __ffs(fail) - 1; fail &= fail - 1;
        uint32_t rawAB[2] = {0u, 0u};
#pragma unroll
        for (int t2 = 0; t2 < 2; ++t2) {
            __syncthreads();
            for (int i = tid; i < 257; i += 1024) Hf[i] = 0u;
            __syncthreads();
            if (row16 == rho) {
#pragma unroll
                for (int i = 0; i < 10; ++i) {
                    uint32_t xx = sc[i].x, yy = sc[i].y;
                    atomicAdd(&Hf[mapkey(xx & 0xFFFFu) >> 8], 1u);
                    atomicAdd(&Hf[mapkey(xx >> 16) >> 8], 1u);
                    atomicAdd(&Hf[mapkey(yy & 0xFFFFu) >> 8], 1u);
                    atomicAdd(&Hf[mapkey(yy >> 16) >> 8], 1u);
                }
            }
            __syncthreads();
            if (w == 0) {
                uint32_t c4[4];
#pragma unroll
                for (int i = 0; i < 4; ++i) c4[i] = Hf[lane * 4 + i];
                uint32_t binM, rem;
                select_from_counts(c4, 255u + (uint32_t)t2, lane, &binM, &rem);
                if (lane == 0) { fb[0] = binM; fb[1] = rem; }
            }
            __syncthreads();
            const uint32_t binM = fb[0], rem = fb[1];
            for (int i = tid; i < 257; i += 1024) Hf[i] = 0u;
            __syncthreads();
            if (row16 == rho) {
#pragma unroll
                for (int i = 0; i < 10; ++i) {
                    uint32_t kk4[4] = {sc[i].x & 0xFFFFu, sc[i].x >> 16,
                                       sc[i].y & 0xFFFFu, sc[i].y >> 16};
#pragma unroll
                    for (int q = 0; q < 4; ++q) {
                        uint32_t mk = mapkey(kk4[q]);
                        if ((mk >> 8) == binM) atomicAdd(&Hf[mk & 255u], 1u);
                    }
                }
            }
            __syncthreads();
            if (w == 0) {
                uint32_t c4[4];
#pragma unroll
                for (int i = 0; i < 4; ++i) c4[i] = Hf[lane * 4 + i];
                uint32_t low, r2;
                select_from_counts(c4, rem, lane, &low, &r2);
                rawAB[t2] = unmapkey((binM << 8) | low);
            }
        }
        __syncthreads();
        if (tid == 0) {
            float fA = bf2f(rawAB[0]), fB = bf2f(rawAB[1]);
            thrs[rho] = fA + 0.9f * (fB - fA);
        }
        __syncthreads();
    }
    __syncthreads();

    // ---------------- P3: softmax + PV from registers ----------------
    const float thr = thrs[row16];
    const int* amq2 = amask + b * SS + quad * 4;
    const ushort_t* bbase = vt + (size_t)bh * NKB * 2048 + lane * 8;

    const uint32_t ow = (row16 == 0) ? 0x3F803F80u : 0u;
    uint4 ov; ov.x = ow; ov.y = ow; ov.z = ow; ov.w = ow;
    bf16x8 onesf; *(uint4*)&onesf = ov;

    f32x4 acc[4];
#pragma unroll
    for (int i = 0; i < 4; ++i) acc[i] = (f32x4){0.f, 0.f, 0.f, 0.f};
    f32x4 acc5 = (f32x4){0.f, 0.f, 0.f, 0.f};

#pragma unroll
    for (int j = 0; j < 5; ++j) {
        const int kb = w * 5 + j;
        uint4 bfrag[4];
#pragma unroll
        for (int nt = 0; nt < 4; ++nt)
            bfrag[nt] = *(const uint4*)(bbase + (size_t)kb * 2048 + nt * 512);
        const bool masked = (kb >= 16);
        int4 mv0 = {1, 1, 1, 1}, mv1 = {1, 1, 1, 1};
        if (masked) {
            mv0 = *(const int4*)(amq2 + kb * 32 - MEMM);
            mv1 = *(const int4*)(amq2 + kb * 32 - MEMM + 16);
        }
        const uint2 sA = sc[2 * j], sB = sc[2 * j + 1];
        uint32_t u[8] = {sA.x & 0xFFFFu, sA.x >> 16, sA.y & 0xFFFFu, sA.y >> 16,
                         sB.x & 0xFFFFu, sB.x >> 16, sB.y & 0xFFFFu, sB.y >> 16};
        int mm[8] = {mv0.x, mv0.y, mv0.z, mv0.w, mv1.x, mv1.y, mv1.z, mv1.w};
        float wv[8];
#pragma unroll
        for (int e = 0; e < 8; ++e) {
            float s = bf2f(u[e]);
            bool keep = (s >= thr);
            if (masked) keep = keep && (mm[e] != 0);
            wv[e] = keep ? __expf(s) : 0.f;
        }
        uint4 aq;
        asm("v_cvt_pk_bf16_f32 %0, %1, %2" : "=v"(aq.x) : "v"(wv[0]), "v"(wv[1]));
        asm("v_cvt_pk_bf16_f32 %0, %1, %2" : "=v"(aq.y) : "v"(wv[2]), "v"(wv[3]));
        asm("v_cvt_pk_bf16_f32 %0, %1, %2" : "=v"(aq.z) : "v"(wv[4]), "v"(wv[5]));
        asm("v_cvt_pk_bf16_f32 %0, %1, %2" : "=v"(aq.w) : "v"(wv[6]), "v"(wv[7]));
        bf16x8 af;
        *(uint4*)&af = aq;
#pragma unroll
        for (int nt = 0; nt < 4; ++nt) {
            bf16x8 bf;
            *(uint4*)&bf = bfrag[nt];
            acc[nt] = __builtin_amdgcn_mfma_f32_16x16x32_bf16(af, bf, acc[nt], 0, 0, 0);
        }
        acc5 = __builtin_amdgcn_mfma_f32_16x16x32_bf16(af, onesf, acc5, 0, 0, 0);
    }

    // ---- combine 16 waves -> wave 0 (red aliases U: hist dead) ----
    __syncthreads();
    float* redf = (float*)U;   // [8][64][21] = 43 KB
#define RED(i) (redf + ((size_t)(i) * 64 + lane) * 21)
    if (w >= 8) {
        float* d = RED(w - 8);
#pragma unroll
        for (int nt = 0; nt < 4; ++nt)
#pragma unroll
            for (int r = 0; r < 4; ++r) d[nt * 4 + r] = acc[nt][r];
#pragma unroll
        for (int r = 0; r < 4; ++r) d[16 + r] = acc5[r];
    }
    __syncthreads();
    if (w < 8) {
        const float* s = RED(w);
#pragma unroll
        for (int nt = 0; nt < 4; ++nt)
#pragma unroll
            for (int r = 0; r < 4; ++r) acc[nt][r] += s[nt * 4 + r];
#pragma unroll
        for (int r = 0; r < 4; ++r) acc5[r] += s[16 + r];
    }
    __syncthreads();
    if (w >= 4 && w < 8) {
        float* d = RED(w - 4);
#pragma unroll
        for (int nt = 0; nt < 4; ++nt)
#pragma unroll
            for (int r = 0; r < 4; ++r) d[nt * 4 + r] = acc[nt][r];
#pragma unroll
        for (int r = 0; r < 4; ++r) d[16 + r] = acc5[r];
    }
    __syncthreads();
    if (w < 4) {
        const float* s = RED(w);
#pragma unroll
        for (int nt = 0; nt < 4; ++nt)
#pragma unroll
            for (int r = 0; r < 4; ++r) acc[nt][r] += s[nt * 4 + r];
#pragma unroll
        for (int r = 0; r < 4; ++r) acc5[r] += s[16 + r];
    }
    __syncthreads();
    if (w >= 2 && w < 4) {
        float* d = RED(w - 2);
#pragma unroll
        for (int nt = 0; nt < 4; ++nt)
#pragma unroll
            for (int r = 0; r < 4; ++r) d[nt * 4 + r] = acc[nt][r];
#pragma unroll
        for (int r = 0; r < 4; ++r) d[16 + r] = acc5[r];
    }
    __syncthreads();
    if (w < 2) {
        const float* s = RED(w);
#pragma unroll
        for (int nt = 0; nt < 4; ++nt)
#pragma unroll
            for (int r = 0; r < 4; ++r) acc[nt][r] += s[nt * 4 + r];
#pragma unroll
        for (int r = 0; r < 4; ++r) acc5[r] += s[16 + r];
    }
    __syncthreads();
    if (w == 1) {
        float* d = RED(0);
#pragma unroll
        for (int nt = 0; nt < 4; ++nt)
#pragma unroll
            for (int r = 0; r < 4; ++r) d[nt * 4 + r] = acc[nt][r];
#pragma unroll
        for (int r = 0; r < 4; ++r) d[16 + r] = acc5[r];
    }
    __syncthreads();
    if (w == 0) {
        const float* s = RED(0);
#pragma unroll
        for (int nt = 0; nt < 4; ++nt)
#pragma unroll
            for (int r = 0; r < 4; ++r) acc[nt][r] += s[nt * 4 + r];
#pragma unroll
        for (int r = 0; r < 4; ++r) acc5[r] += s[16 + r];

        float rinv[4];
#pragma unroll
        for (int r = 0; r < 4; ++r) {
            float rs = __shfl(acc5[r], quad * 16, 64);
            rinv[r] = 1.0f / rs;
        }
#pragma unroll
        for (int nt = 0; nt < 4; ++nt) {
#pragma unroll
            for (int r = 0; r < 4; ++r) {
                int row = quad * 4 + r;
                float val = acc[nt][r] * rinv[r];
                attn_bf[((size_t)b * SS + m0 + row) * DD + h * HDD + nt * 16 + row16] = f2bf(val);
            }
        }
    }
#undef RED
}

extern "C" void kernel_launch(void* const* d_in, const int* in_sizes, int n_in,
                              void* d_out, int out_size, void* d_ws, size_t ws_size,
                              hipStream_t stream)
{
    const float* hidden = (const float*)d_in[0];
    const int*   amask  = (const int*)d_in[1];
    const float* past_k = (const float*)d_in[2];
    const float* past_v = (const float*)d_in[3];
    const float* Wq = (const float*)d_in[4];
    const float* bq = (const float*)d_in[5];
    const float* Wk = (const float*)d_in[6];
    const float* bk = (const float*)d_in[7];
    const float* Wv = (const float*)d_in[8];
    const float* bv = (const float*)d_in[9];
    const float* Wo = (const float*)d_in[10];
    const float* bo = (const float*)d_in[11];

    float* out    = (float*)d_out;
    float* nk_out = out + (size_t)BB * SS * DD;
    float* nv_out = nk_out + (size_t)BB * HH * MEMM * HDD;

    char* base = (char*)d_ws;
    size_t off = 0;
    auto alloc = [&](size_t bytes) {
        char* p = base + off;
        off += (bytes + 255) & ~(size_t)255;
        return p;
    };
    ushort_t* hb    = (ushort_t*)alloc((size_t)BB * SS * DD * 2);            // 8 MB
    ushort_t* WtAll = (ushort_t*)alloc((size_t)4 * DD * DD * 2);             // 8 MB
    ushort_t* q_bf  = (ushort_t*)alloc((size_t)BB * HH * SS * HDD * 2);      // 8 MB
    ushort_t* kbf   = (ushort_t*)alloc((size_t)BB * HH * KTOT * HDD * 2);    // 10 MB
    ushort_t* vbf   = (ushort_t*)alloc((size_t)BB * HH * KTOT * HDD * 2);    // 10 MB
    ushort_t* vt    = (ushort_t*)alloc((size_t)BB * HH * NKB * 4 * 512 * 2); // 10.5 MB packed
    ushort_t* abf   = (ushort_t*)alloc((size_t)BB * SS * DD * 2);            // 8 MB

    dim3 blk(256);

    cast_hidden_kernel<<<dim3(1024), blk, 0, stream>>>(hidden, hb);
    transw_kernel<<<dim3(16, 16, 4), blk, 0, stream>>>(Wq, Wk, Wv, Wo, WtAll);
    // fused QKV: one GEMM, N=3072 (Wq|Wk|Wv transposes adjacent in WtAll)
    gemm128_kernel<<<dim3(24, 32), blk, 0, stream>>>(
        hb, WtAll, 1, bq, bk, bv, nullptr, q_bf, kbf, vbf, nk_out, nv_out);
    cast_past_kernel<<<dim3(4096), blk, 0, stream>>>(past_k, past_v, kbf, vbf);
    transpose_v_kernel<<<dim3(KTOT / 64, BB * HH), blk, 0, stream>>>(vbf, vt);

    // fused attention: one 16-wave block per 16-row panel, scores in registers
    fused_attn_kernel<<<dim3(BB * HH * (SS / 16)), dim3(1024), 0, stream>>>(
        q_bf, kbf, vt, amask, abf);

    // O-projection
    gemm128_kernel<<<dim3(8, 32), blk, 0, stream>>>(
        abf, WtAll + (size_t)3 * DD * DD, 0, bo, nullptr, nullptr, out,
        nullptr, nullptr, nullptr, nullptr, nullptr);
}